// Round 1
// baseline (1702.008 us; speedup 1.0000x reference)
//
#include <hip/hip_runtime.h>

#define NN 245760
#define NB 4096
#define NPER 60
#define NE 2000000
#define KSEL 30
#define NDRUG 1024
#define NDIS 2048

// ---------------- graph degree / CSR ----------------
__global__ void k_count(const int* __restrict__ ei, int* __restrict__ cnt) {
    for (int e = blockIdx.x * blockDim.x + threadIdx.x; e < NE; e += gridDim.x * blockDim.x)
        atomicAdd(&cnt[ei[NE + e]], 1);
}

__global__ void k_dinv(const int* __restrict__ cnt, float* __restrict__ dinv) {
    int i = blockIdx.x * blockDim.x + threadIdx.x;
    if (i < NN) dinv[i] = 1.0f / sqrtf((float)cnt[i] + 1.0f);
}

__global__ void k_block_sums(const int* __restrict__ deg, int* __restrict__ sums) {
    int t = threadIdx.x, b = blockIdx.x;
    const int4* p = (const int4*)(deg + b * 1024);
    int4 v = p[t];
    int s = v.x + v.y + v.z + v.w;
    __shared__ int red[256];
    red[t] = s; __syncthreads();
    for (int off = 128; off > 0; off >>= 1) {
        if (t < off) red[t] += red[t + off];
        __syncthreads();
    }
    if (t == 0) sums[b] = red[0];
}

__global__ void k_scan_sums(int* __restrict__ sums, int nb) {
    __shared__ int lds[256];
    int t = threadIdx.x;
    int v = (t < nb) ? sums[t] : 0;
    lds[t] = v; __syncthreads();
    for (int off = 1; off < 256; off <<= 1) {
        int add = (t >= off) ? lds[t - off] : 0;
        __syncthreads();
        lds[t] += add;
        __syncthreads();
    }
    if (t < nb) sums[t] = lds[t] - v;   // exclusive
}

__global__ void k_scan_blocks(const int* __restrict__ deg, const int* __restrict__ sums,
                              int* __restrict__ rowp) {
    int t = threadIdx.x, b = blockIdx.x;
    const int4* p = (const int4*)(deg + b * 1024);
    int4 v = p[t];
    int s = v.x + v.y + v.z + v.w;
    __shared__ int lds[256];
    lds[t] = s; __syncthreads();
    for (int off = 1; off < 256; off <<= 1) {
        int add = (t >= off) ? lds[t - off] : 0;
        __syncthreads();
        lds[t] += add;
        __syncthreads();
    }
    int excl = lds[t] - s + sums[b];
    int4 o; o.x = excl; o.y = excl + v.x; o.z = o.y + v.y; o.w = o.z + v.z;
    ((int4*)(rowp + b * 1024))[t] = o;
}

__global__ void k_fill(const int* __restrict__ ei, const int* __restrict__ rowp,
                       int* __restrict__ fill, int* __restrict__ csr) {
    for (int e = blockIdx.x * blockDim.x + threadIdx.x; e < NE; e += gridDim.x * blockDim.x) {
        int s = ei[e], d = ei[NE + e];
        int pos = rowp[d] + atomicAdd(&fill[d], 1);
        csr[pos] = s;
    }
}

// out[d, colofs+j] = relu(dinv_d*(sum_s dinv_s*h[s,j] + dinv_d*h[d,j]) + b[j]), out stride 64
__global__ void k_gcn_agg(const float* __restrict__ h, const int* __restrict__ csr,
                          const int* __restrict__ rowp, const int* __restrict__ cnt,
                          const float* __restrict__ dinv, const float* __restrict__ bias,
                          float* __restrict__ out, int colofs) {
    int t = threadIdx.x;
    int j = t & 31;
    int d = blockIdx.x * 8 + (t >> 5);
    float dd = dinv[d];
    int start = rowp[d], c = cnt[d];
    float acc = dd * h[d * 32 + j];
    for (int k = 0; k < c; k++) {
        int s = csr[start + k];
        acc += dinv[s] * h[s * 32 + j];
    }
    out[d * 64 + colofs + j] = fmaxf(dd * acc + bias[j], 0.0f);
}

// ---------------- generic tiled fp32 GEMM ----------------
// MODE 0: A row r at A + r*lda (first K cols). MODE 1: conv2 im2col row base ((r/11)*15+r%11)*128
template <int MODE>
__global__ __launch_bounds__(256) void k_gemm(const float* __restrict__ A, const float* __restrict__ Bm,
                                              float* __restrict__ C, const float* __restrict__ bias,
                                              int M, int N, int K, int lda, int relu) {
    __shared__ float As[16 * 68];
    __shared__ float Bs[16 * 64];
    int t = threadIdx.x;
    int tx = t & 15, ty = t >> 4;
    int r0 = blockIdx.x * 64, c0 = blockIdx.y * 64;
    float acc[4][4] = {};
    int arow = r0 + (t >> 2);
    long abase;
    if (MODE == 0) abase = (long)arow * lda;
    else { int bb = arow / 11, tt2 = arow % 11; abase = (long)(bb * 15 + tt2) * 128; }
    int aq = (t & 3) * 4;
    int brow = t >> 4;
    int bc = (t & 15) * 4;
    for (int k0 = 0; k0 < K; k0 += 16) {
        float4 av = *(const float4*)(A + abase + k0 + aq);
        int ar = t >> 2;
        As[(aq + 0) * 68 + ar] = av.x;
        As[(aq + 1) * 68 + ar] = av.y;
        As[(aq + 2) * 68 + ar] = av.z;
        As[(aq + 3) * 68 + ar] = av.w;
        int gc = c0 + bc;
        const float* bp = Bm + (long)(k0 + brow) * N + gc;
        float4 bv;
        if (gc + 3 < N) bv = *(const float4*)bp;
        else {
            bv.x = (gc < N) ? bp[0] : 0.f;
            bv.y = (gc + 1 < N) ? bp[1] : 0.f;
            bv.z = (gc + 2 < N) ? bp[2] : 0.f;
            bv.w = 0.f;
        }
        *(float4*)&Bs[brow * 64 + bc] = bv;
        __syncthreads();
#pragma unroll
        for (int kk = 0; kk < 16; kk++) {
            float4 a4 = *(const float4*)&As[kk * 68 + ty * 4];
            float4 b4 = *(const float4*)&Bs[kk * 64 + tx * 4];
            float aa[4] = {a4.x, a4.y, a4.z, a4.w};
            float bb2[4] = {b4.x, b4.y, b4.z, b4.w};
#pragma unroll
            for (int i = 0; i < 4; i++)
#pragma unroll
                for (int j = 0; j < 4; j++) acc[i][j] += aa[i] * bb2[j];
        }
        __syncthreads();
    }
#pragma unroll
    for (int i = 0; i < 4; i++) {
        int row = r0 + ty * 4 + i;
#pragma unroll
        for (int j = 0; j < 4; j++) {
            int col = c0 + tx * 4 + j;
            if (col < N) {
                float v = acc[i][j] + (bias ? bias[col] : 0.f);
                if (relu) v = fmaxf(v, 0.f);
                C[(long)row * N + col] = v;
            }
        }
    }
}

// ---------------- stable top-K selection ----------------
__global__ void k_select(const float* __restrict__ cs, int* __restrict__ sel) {
    __shared__ float kk[240];
    int t = threadIdx.x;
    int b0 = blockIdx.x * 4;
    if (t < 240) kk[t] = cs[((long)(b0 * 60 + t)) * 64 + 63];
    __syncthreads();
    if (t < 240) {
        int lb = t / 60, i = t % 60;
        float key = kk[lb * 60 + i];
        int r = 0;
        for (int j = 0; j < 60; j++) {
            float kj = kk[lb * 60 + j];
            r += (kj > key) || (kj == key && j < i);
        }
        if (r < KSEL) sel[(b0 + lb) * KSEL + r] = (b0 + lb) * 60 + i;
    }
}

// ---------------- conv1 (stride-64) + relu + maxpool2 ----------------
__global__ __launch_bounds__(256) void k_conv1_pool(const float* __restrict__ cs, const int* __restrict__ sel,
                                                    const float* __restrict__ c1w, const float* __restrict__ c1b,
                                                    float* __restrict__ po) {
    __shared__ float xs[30 * 64];
    __shared__ float w[64 * 129];
    __shared__ float cv[30 * 128];
    int t = threadIdx.x, b = blockIdx.x;
    for (int idx = t; idx < 1920; idx += 256) {
        int i = idx >> 6, c = idx & 63;
        xs[idx] = cs[(long)sel[b * KSEL + i] * 64 + c];
    }
    for (int f = t; f < 8192; f += 256) {
        int oc = f >> 6, tt = f & 63;
        w[tt * 129 + oc] = c1w[f];
    }
    __syncthreads();
    int oc = t & 127, half = t >> 7;
    float acc[15];
#pragma unroll
    for (int k = 0; k < 15; k++) acc[k] = 0.f;
    int kbase = half * 15;
    for (int tt = 0; tt < 64; tt++) {
        float wv = w[tt * 129 + oc];
#pragma unroll
        for (int k = 0; k < 15; k++) acc[k] += wv * xs[(kbase + k) * 64 + tt];
    }
    float bb = c1b[oc];
#pragma unroll
    for (int k = 0; k < 15; k++) cv[(kbase + k) * 128 + oc] = fmaxf(acc[k] + bb, 0.f);
    __syncthreads();
    for (int idx = t; idx < 1920; idx += 256) {
        int k2 = idx >> 7, c = idx & 127;
        po[(long)b * 1920 + idx] = fmaxf(cv[(2 * k2) * 128 + c], cv[(2 * k2 + 1) * 128 + c]);
    }
}

// ---------------- weight prep ----------------
__global__ void k_w2col(const float* __restrict__ c2w, float* __restrict__ o) {
    int idx = blockIdx.x * blockDim.x + threadIdx.x;
    if (idx >= 640 * 256) return;
    int r = idx >> 8, oc = idx & 255;
    int tap = r >> 7, ic = r & 127;
    o[idx] = c2w[(oc * 128 + ic) * 5 + tap];
}

__global__ void k_w1p(const float* __restrict__ w, float* __restrict__ o) {
    int idx = blockIdx.x * blockDim.x + threadIdx.x;
    if (idx >= 2816 * 128) return;
    int r = idx >> 7, j = idx & 127;
    int tt = r / 256, oc = r % 256;
    o[idx] = w[(oc * 11 + tt) * 128 + j];
}

// ---------------- lin2 + bn + relu ----------------
__global__ void k_lin2_bn(const float* __restrict__ x, const float* __restrict__ w,
                          const float* __restrict__ b, const float* __restrict__ g,
                          const float* __restrict__ bb, float* __restrict__ o) {
    int t = blockIdx.x * blockDim.x + threadIdx.x;
    int j = t & 31, bi = t >> 5;
    const float* xr = x + (long)bi * 128;
    float acc = b[j];
    for (int k = 0; k < 128; k++) acc += xr[k] * w[k * 32 + j];
    o[bi * 32 + j] = fmaxf(acc * g[j] + bb[j], 0.f);
}

// ---------------- dense GCN helpers ----------------
__global__ void k_dense_deg(const float* __restrict__ adj, float* __restrict__ dinv, int n) {
    int lane = threadIdx.x & 63;
    int row = (blockIdx.x * blockDim.x + threadIdx.x) >> 6;
    if (row >= n) return;
    const float* r = adj + (long)row * n;
    float s = 0.f;
    for (int j = lane; j < n; j += 64) s += r[j];
    for (int off = 32; off > 0; off >>= 1) s += __shfl_down(s, off, 64);
    if (lane == 0) {
        float deg = s - r[row] + 1.0f;
        dinv[row] = (deg > 0.f) ? 1.0f / sqrtf(deg) : 0.f;
    }
}

__global__ void k_scale_rows(float* __restrict__ tt, const float* __restrict__ dinv, int n, int cols) {
    int idx = blockIdx.x * blockDim.x + threadIdx.x;
    if (idx >= n * cols) return;
    tt[idx] *= dinv[idx / cols];
}

__global__ void k_gcn_fixup(const float* __restrict__ g, const float* __restrict__ tj,
                            const float* __restrict__ adj, const float* __restrict__ dinv,
                            const float* __restrict__ bias, float* __restrict__ out, int n, int cols) {
    int idx = blockIdx.x * blockDim.x + threadIdx.x;
    if (idx >= n * cols) return;
    int i = idx / cols, j = idx % cols;
    float v = dinv[i] * (g[idx] + (1.0f - adj[(long)i * n + i]) * tj[idx]) + bias[j];
    out[idx] = fmaxf(v, 0.f);
}

// ---------------- final fused MLP ----------------
__global__ __launch_bounds__(256) void k_final(const float* __restrict__ hfin, const int* __restrict__ node,
                                               const float* __restrict__ dio, const float* __restrict__ dro,
                                               const float* __restrict__ pp,
                                               const float* __restrict__ fw, const float* __restrict__ fb,
                                               const float* __restrict__ f2w, const float* __restrict__ f2b,
                                               float* __restrict__ out) {
    __shared__ float w[64 * 32];
    __shared__ float w2[32];
    int t = threadIdx.x;
    for (int f = t; f < 2048; f += 256) w[f] = fw[f];
    if (t < 32) w2[t] = f2w[t];
    __syncthreads();
    int b = blockIdx.x * 256 + t;
    float p = *pp, q = 1.0f - p;
    float zin[64];
#pragma unroll
    for (int i = 0; i < 32; i++) zin[i] = hfin[b * 32 + i] * p;
    int n0 = node[b * 2], n1 = node[b * 2 + 1];
#pragma unroll
    for (int i = 0; i < 16; i++) zin[32 + i] = dio[n0 * 16 + i] * q;
#pragma unroll
    for (int i = 0; i < 16; i++) zin[48 + i] = dro[n1 * 16 + i] * q;
    float res = f2b[0];
    for (int j = 0; j < 32; j++) {
        float acc = fb[j];
#pragma unroll
        for (int i = 0; i < 64; i++) acc += zin[i] * w[i * 32 + j];
        res += fmaxf(acc, 0.f) * w2[j];
    }
    out[b] = res;
}

// ---------------- host ----------------
extern "C" void kernel_launch(void* const* d_in, const int* in_sizes, int n_in,
                              void* d_out, int out_size, void* d_ws, size_t ws_size,
                              hipStream_t stream) {
    const float* x        = (const float*)d_in[0];
    const int*   ei       = (const int*)d_in[1];
    const int*   node     = (const int*)d_in[3];
    const float* di_sim   = (const float*)d_in[4];
    const float* dr_sim   = (const float*)d_in[5];
    const float* drug_adj = (const float*)d_in[6];
    const float* dis_adj  = (const float*)d_in[7];
    const float* p        = (const float*)d_in[8];
    const float* W1 = (const float*)d_in[9],  *b1 = (const float*)d_in[10];
    const float* W2 = (const float*)d_in[11], *b2 = (const float*)d_in[12];
    const float* W3 = (const float*)d_in[13], *b3 = (const float*)d_in[14];
    const float* W4 = (const float*)d_in[15], *b4 = (const float*)d_in[16];
    const float* lin_di_w = (const float*)d_in[17], *lin_di_b = (const float*)d_in[18];
    const float* lin_dr_w = (const float*)d_in[19], *lin_dr_b = (const float*)d_in[20];
    const float* c1w = (const float*)d_in[21], *c1b = (const float*)d_in[22];
    const float* c2w = (const float*)d_in[23], *c2b = (const float*)d_in[24];
    const float* lin1w = (const float*)d_in[25], *lin1b = (const float*)d_in[26];
    const float* lin2w = (const float*)d_in[27], *lin2b = (const float*)d_in[28];
    const float* bng = (const float*)d_in[29], *bnb = (const float*)d_in[30];
    const float* fcsw = (const float*)d_in[31], *fcsb = (const float*)d_in[32];
    const float* fcs2w = (const float*)d_in[33], *fcs2b = (const float*)d_in[34];

    char* ws = (char*)d_ws;
    size_t o = 0;
    auto alloc = [&](size_t bytes) { size_t r = o; o += (bytes + 255) & ~(size_t)255; return r; };
    int*   csr     = (int*)(ws + alloc((size_t)NE * 4));
    int*   degcnt  = (int*)(ws + alloc((size_t)NN * 4));
    int*   rowp    = (int*)(ws + alloc((size_t)NN * 4));
    int*   fillc   = (int*)(ws + alloc((size_t)NN * 4));
    float* dinvn   = (float*)(ws + alloc((size_t)NN * 4));
    float* hbuf    = (float*)(ws + alloc((size_t)NN * 32 * 4));  // reused as pool_out (B*15*128)
    float* cs      = (float*)(ws + alloc((size_t)NN * 64 * 4));  // reused as act2 (B*11*256)
    int*   sel     = (int*)(ws + alloc((size_t)NB * KSEL * 4));
    float* lin1o   = (float*)(ws + alloc((size_t)NB * 128 * 4));
    float* hfin    = (float*)(ws + alloc((size_t)NB * 32 * 4));
    float* w2col   = (float*)(ws + alloc((size_t)640 * 256 * 4));
    float* w1p     = (float*)(ws + alloc((size_t)2816 * 128 * 4));
    int*   sums    = (int*)(ws + alloc(256 * 4));
    float* ddin_di = (float*)(ws + alloc((size_t)NDRUG * 4));
    float* de_di   = (float*)(ws + alloc((size_t)NDRUG * 256 * 4));
    float* dt_di   = (float*)(ws + alloc((size_t)NDRUG * 64 * 4));
    float* dg_di   = (float*)(ws + alloc((size_t)NDRUG * 64 * 4));
    float* df_di   = (float*)(ws + alloc((size_t)NDRUG * 64 * 4));
    float* dt2_di  = (float*)(ws + alloc((size_t)NDRUG * 16 * 4));
    float* dg2_di  = (float*)(ws + alloc((size_t)NDRUG * 16 * 4));
    float* do_di   = (float*)(ws + alloc((size_t)NDRUG * 16 * 4));
    float* ddin_dr = (float*)(ws + alloc((size_t)NDIS * 4));
    float* de_dr   = (float*)(ws + alloc((size_t)NDIS * 256 * 4));
    float* dt_dr   = (float*)(ws + alloc((size_t)NDIS * 64 * 4));
    float* dg_dr   = (float*)(ws + alloc((size_t)NDIS * 64 * 4));
    float* df_dr   = (float*)(ws + alloc((size_t)NDIS * 64 * 4));
    float* dt2_dr  = (float*)(ws + alloc((size_t)NDIS * 16 * 4));
    float* dg2_dr  = (float*)(ws + alloc((size_t)NDIS * 16 * 4));
    float* do_dr   = (float*)(ws + alloc((size_t)NDIS * 16 * 4));
    float* pool = hbuf;   // alias after GCN done
    float* act2 = cs;     // alias after conv1 done

    hipMemsetAsync(degcnt, 0, (size_t)NN * 4, stream);
    hipMemsetAsync(fillc, 0, (size_t)NN * 4, stream);

    // CSR build
    k_count<<<2048, 256, 0, stream>>>(ei, degcnt);
    k_dinv<<<(NN + 255) / 256, 256, 0, stream>>>(degcnt, dinvn);
    k_block_sums<<<240, 256, 0, stream>>>(degcnt, sums);
    k_scan_sums<<<1, 256, 0, stream>>>(sums, 240);
    k_scan_blocks<<<240, 256, 0, stream>>>(degcnt, sums, rowp);
    k_fill<<<2048, 256, 0, stream>>>(ei, rowp, fillc, csr);

    // GCN conv 1: h = x@W1 ; x1 = relu(agg + b1) -> cs[:, 0:32]
    k_gemm<0><<<dim3(NN / 64, 1), 256, 0, stream>>>(x, W1, hbuf, nullptr, NN, 32, 64, 64, 0);
    k_gcn_agg<<<NN / 8, 256, 0, stream>>>(hbuf, csr, rowp, degcnt, dinvn, b1, cs, 0);
    // GCN conv 2: h = x1@W2 ; x2 -> cs[:, 32:64]
    k_gemm<0><<<dim3(NN / 64, 1), 256, 0, stream>>>(cs, W2, hbuf, nullptr, NN, 32, 32, 64, 0);
    k_gcn_agg<<<NN / 8, 256, 0, stream>>>(hbuf, csr, rowp, degcnt, dinvn, b2, cs, 32);

    // stable top-K selection per batch
    k_select<<<NB / 4, 256, 0, stream>>>(cs, sel);

    // weight prep
    k_w2col<<<(640 * 256 + 255) / 256, 256, 0, stream>>>(c2w, w2col);
    k_w1p<<<(2816 * 128 + 255) / 256, 256, 0, stream>>>(lin1w, w1p);

    // conv1 + pool  (writes pool = hbuf, reads cs)
    k_conv1_pool<<<NB, 256, 0, stream>>>(cs, sel, c1w, c1b, pool);

    // conv2 as im2col GEMM: (B*11, 640) @ (640,256) -> act2 (= cs)
    k_gemm<1><<<dim3(45056 / 64, 4), 256, 0, stream>>>(pool, w2col, act2, c2b, 45056, 256, 640, 0, 1);
    // lin1: (B, 2816) @ (2816, 128)
    k_gemm<0><<<dim3(NB / 64, 2), 256, 0, stream>>>(act2, w1p, lin1o, lin1b, NB, 128, 2816, 2816, 1);
    // lin2 + bn
    k_lin2_bn<<<NB * 32 / 256, 256, 0, stream>>>(lin1o, lin2w, lin2b, bng, bnb, hfin);

    // ---- drug path ----
    k_dense_deg<<<NDRUG * 64 / 256, 256, 0, stream>>>(drug_adj, ddin_di, NDRUG);
    k_gemm<0><<<dim3(NDRUG / 64, 4), 256, 0, stream>>>(di_sim, lin_di_w, de_di, lin_di_b, NDRUG, 256, NDRUG, NDRUG, 0);
    k_gemm<0><<<dim3(NDRUG / 64, 1), 256, 0, stream>>>(de_di, W3, dt_di, nullptr, NDRUG, 64, 256, 256, 0);
    k_scale_rows<<<(NDRUG * 64 + 255) / 256, 256, 0, stream>>>(dt_di, ddin_di, NDRUG, 64);
    k_gemm<0><<<dim3(NDRUG / 64, 1), 256, 0, stream>>>(drug_adj, dt_di, dg_di, nullptr, NDRUG, 64, NDRUG, NDRUG, 0);
    k_gcn_fixup<<<(NDRUG * 64 + 255) / 256, 256, 0, stream>>>(dg_di, dt_di, drug_adj, ddin_di, b3, df_di, NDRUG, 64);
    k_gemm<0><<<dim3(NDRUG / 64, 1), 256, 0, stream>>>(df_di, W4, dt2_di, nullptr, NDRUG, 16, 64, 64, 0);
    k_scale_rows<<<(NDRUG * 16 + 255) / 256, 256, 0, stream>>>(dt2_di, ddin_di, NDRUG, 16);
    k_gemm<0><<<dim3(NDRUG / 64, 1), 256, 0, stream>>>(drug_adj, dt2_di, dg2_di, nullptr, NDRUG, 16, NDRUG, NDRUG, 0);
    k_gcn_fixup<<<(NDRUG * 16 + 255) / 256, 256, 0, stream>>>(dg2_di, dt2_di, drug_adj, ddin_di, b4, do_di, NDRUG, 16);

    // ---- disease path ----
    k_dense_deg<<<NDIS * 64 / 256, 256, 0, stream>>>(dis_adj, ddin_dr, NDIS);
    k_gemm<0><<<dim3(NDIS / 64, 4), 256, 0, stream>>>(dr_sim, lin_dr_w, de_dr, lin_dr_b, NDIS, 256, NDIS, NDIS, 0);
    k_gemm<0><<<dim3(NDIS / 64, 1), 256, 0, stream>>>(de_dr, W3, dt_dr, nullptr, NDIS, 64, 256, 256, 0);
    k_scale_rows<<<(NDIS * 64 + 255) / 256, 256, 0, stream>>>(dt_dr, ddin_dr, NDIS, 64);
    k_gemm<0><<<dim3(NDIS / 64, 1), 256, 0, stream>>>(dis_adj, dt_dr, dg_dr, nullptr, NDIS, 64, NDIS, NDIS, 0);
    k_gcn_fixup<<<(NDIS * 64 + 255) / 256, 256, 0, stream>>>(dg_dr, dt_dr, dis_adj, ddin_dr, b3, df_dr, NDIS, 64);
    k_gemm<0><<<dim3(NDIS / 64, 1), 256, 0, stream>>>(df_dr, W4, dt2_dr, nullptr, NDIS, 16, 64, 64, 0);
    k_scale_rows<<<(NDIS * 16 + 255) / 256, 256, 0, stream>>>(dt2_dr, ddin_dr, NDIS, 16);
    k_gemm<0><<<dim3(NDIS / 64, 1), 256, 0, stream>>>(dis_adj, dt2_dr, dg2_dr, nullptr, NDIS, 16, NDIS, NDIS, 0);
    k_gcn_fixup<<<(NDIS * 16 + 255) / 256, 256, 0, stream>>>(dg2_dr, dt2_dr, dis_adj, ddin_dr, b4, do_dr, NDIS, 16);

    // final
    k_final<<<NB / 256, 256, 0, stream>>>(hfin, node, do_di, do_dr, p, fcsw, fcsb, fcs2w, fcs2b, (float*)d_out);
}

// Round 2
// 988.957 us; speedup vs baseline: 1.7210x; 1.7210x over previous
//
#include <hip/hip_runtime.h>

#define NN 245760
#define NB 4096
#define NPER 60
#define NE 2000000
#define KSEL 30
#define NDRUG 1024
#define NDIS 2048

// ---------------- graph degree / CSR ----------------
__global__ void k_count(const int* __restrict__ ei, int* __restrict__ cnt) {
    for (int e = blockIdx.x * blockDim.x + threadIdx.x; e < NE; e += gridDim.x * blockDim.x)
        atomicAdd(&cnt[ei[NE + e]], 1);
}

__global__ void k_dinv(const int* __restrict__ cnt, float* __restrict__ dinv) {
    int i = blockIdx.x * blockDim.x + threadIdx.x;
    if (i < NN) dinv[i] = 1.0f / sqrtf((float)cnt[i] + 1.0f);
}

__global__ void k_block_sums(const int* __restrict__ deg, int* __restrict__ sums) {
    int t = threadIdx.x, b = blockIdx.x;
    const int4* p = (const int4*)(deg + b * 1024);
    int4 v = p[t];
    int s = v.x + v.y + v.z + v.w;
    __shared__ int red[256];
    red[t] = s; __syncthreads();
    for (int off = 128; off > 0; off >>= 1) {
        if (t < off) red[t] += red[t + off];
        __syncthreads();
    }
    if (t == 0) sums[b] = red[0];
}

__global__ void k_scan_sums(int* __restrict__ sums, int nb) {
    __shared__ int lds[256];
    int t = threadIdx.x;
    int v = (t < nb) ? sums[t] : 0;
    lds[t] = v; __syncthreads();
    for (int off = 1; off < 256; off <<= 1) {
        int add = (t >= off) ? lds[t - off] : 0;
        __syncthreads();
        lds[t] += add;
        __syncthreads();
    }
    if (t < nb) sums[t] = lds[t] - v;   // exclusive
}

__global__ void k_scan_blocks(const int* __restrict__ deg, const int* __restrict__ sums,
                              int* __restrict__ rowp) {
    int t = threadIdx.x, b = blockIdx.x;
    const int4* p = (const int4*)(deg + b * 1024);
    int4 v = p[t];
    int s = v.x + v.y + v.z + v.w;
    __shared__ int lds[256];
    lds[t] = s; __syncthreads();
    for (int off = 1; off < 256; off <<= 1) {
        int add = (t >= off) ? lds[t - off] : 0;
        __syncthreads();
        lds[t] += add;
        __syncthreads();
    }
    int excl = lds[t] - s + sums[b];
    int4 o; o.x = excl; o.y = excl + v.x; o.z = o.y + v.y; o.w = o.z + v.z;
    ((int4*)(rowp + b * 1024))[t] = o;
}

__global__ void k_fill(const int* __restrict__ ei, const int* __restrict__ rowp,
                       int* __restrict__ fill, int* __restrict__ csr) {
    for (int e = blockIdx.x * blockDim.x + threadIdx.x; e < NE; e += gridDim.x * blockDim.x) {
        int s = ei[e], d = ei[NE + e];
        int pos = rowp[d] + atomicAdd(&fill[d], 1);
        csr[pos] = s;
    }
}

// ---------------- X(M x K, stride lda) @ W(K x 32) -> h(M x 32), K<=64 ----------------
__global__ __launch_bounds__(256) void k_xw(const float* __restrict__ A, const float* __restrict__ W,
                                            float* __restrict__ h, int K, int lda) {
    __shared__ float Xs[64][65];
    __shared__ float Ws[64][32];
    int t = threadIdx.x;
    int r0 = blockIdx.x * 64;
    int kq = K >> 2;
    for (int idx = t; idx < 64 * kq; idx += 256) {
        int row = idx / kq, q = idx % kq;
        float4 v = *(const float4*)(A + (long)(r0 + row) * lda + q * 4);
        Xs[row][q * 4 + 0] = v.x; Xs[row][q * 4 + 1] = v.y;
        Xs[row][q * 4 + 2] = v.z; Xs[row][q * 4 + 3] = v.w;
    }
    for (int idx = t; idx < K * 32; idx += 256) ((float*)Ws)[idx] = W[idx];
    __syncthreads();
    int r = (t >> 3) * 2, c = (t & 7) * 4;
    float4 acc0 = {0, 0, 0, 0}, acc1 = {0, 0, 0, 0};
    for (int k = 0; k < K; k++) {
        float x0 = Xs[r][k], x1 = Xs[r + 1][k];
        float4 w = *(const float4*)&Ws[k][c];
        acc0.x += x0 * w.x; acc0.y += x0 * w.y; acc0.z += x0 * w.z; acc0.w += x0 * w.w;
        acc1.x += x1 * w.x; acc1.y += x1 * w.y; acc1.z += x1 * w.z; acc1.w += x1 * w.w;
    }
    *(float4*)(h + (long)(r0 + r) * 32 + c) = acc0;
    *(float4*)(h + (long)(r0 + r + 1) * 32 + c) = acc1;
}

// out[d, colofs+j] = relu(dinv_d*(sum_s dinv_s*h[s,j] + dinv_d*h[d,j]) + b[j]), out stride 64
// 8 lanes per dest, float4 cols
__global__ void k_gcn_agg(const float* __restrict__ h, const int* __restrict__ csr,
                          const int* __restrict__ rowp, const int* __restrict__ cnt,
                          const float* __restrict__ dinv, const float* __restrict__ bias,
                          float* __restrict__ out, int colofs) {
    int t = threadIdx.x;
    int l = t & 7, g = t >> 3;
    int d = blockIdx.x * 32 + g;
    float dd = dinv[d];
    int start = rowp[d], c = cnt[d];
    float4 hv = *(const float4*)(h + (long)d * 32 + l * 4);
    float4 acc; acc.x = dd * hv.x; acc.y = dd * hv.y; acc.z = dd * hv.z; acc.w = dd * hv.w;
    for (int k = 0; k < c; k++) {
        int s = csr[start + k];
        float ds = dinv[s];
        float4 v = *(const float4*)(h + (long)s * 32 + l * 4);
        acc.x += ds * v.x; acc.y += ds * v.y; acc.z += ds * v.z; acc.w += ds * v.w;
    }
    float4 bv = *(const float4*)(bias + l * 4);
    float* op = out + (long)d * 64 + colofs + l * 4;
    op[0] = fmaxf(dd * acc.x + bv.x, 0.f);
    op[1] = fmaxf(dd * acc.y + bv.y, 0.f);
    op[2] = fmaxf(dd * acc.z + bv.z, 0.f);
    op[3] = fmaxf(dd * acc.w + bv.w, 0.f);
}

// ---------------- 128x128 fp32 GEMM (conv2 im2col) ----------------
// MODE 0: A row r at A + r*lda. MODE 1: im2col row base ((r/11)*15+r%11)*128
template <int MODE>
__global__ __launch_bounds__(256, 2) void k_gemm128(const float* __restrict__ A, const float* __restrict__ Bm,
                                                    float* __restrict__ C, const float* __restrict__ bias,
                                                    int N, int K, int lda, int relu) {
    __shared__ float As[16][132];
    __shared__ float Bs[16][128];
    int t = threadIdx.x;
    int tx = t & 15, ty = t >> 4;
    int r0 = blockIdx.x * 128, c0 = blockIdx.y * 128;
    float acc[8][8] = {};
    int ar = t >> 2;
    int aq = (t & 3) * 4;
    int arow0 = r0 + ar, arow1 = r0 + 64 + ar;
    long ab0, ab1;
    if (MODE == 0) { ab0 = (long)arow0 * lda; ab1 = (long)arow1 * lda; }
    else {
        ab0 = (long)((arow0 / 11) * 15 + arow0 % 11) * 128;
        ab1 = (long)((arow1 / 11) * 15 + arow1 % 11) * 128;
    }
    int brow = t >> 4;
    int bcol = (t & 15) * 8;
    for (int k0 = 0; k0 < K; k0 += 16) {
        float4 a0 = *(const float4*)(A + ab0 + k0 + aq);
        float4 a1 = *(const float4*)(A + ab1 + k0 + aq);
        const float* bp = Bm + (long)(k0 + brow) * N + c0 + bcol;
        float4 b0 = *(const float4*)bp;
        float4 b1 = *(const float4*)(bp + 4);
        As[aq + 0][ar] = a0.x; As[aq + 1][ar] = a0.y; As[aq + 2][ar] = a0.z; As[aq + 3][ar] = a0.w;
        As[aq + 0][64 + ar] = a1.x; As[aq + 1][64 + ar] = a1.y; As[aq + 2][64 + ar] = a1.z; As[aq + 3][64 + ar] = a1.w;
        *(float4*)&Bs[brow][bcol] = b0;
        *(float4*)&Bs[brow][bcol + 4] = b1;
        __syncthreads();
#pragma unroll
        for (int kk = 0; kk < 16; kk++) {
            float4 av0 = *(const float4*)&As[kk][ty * 8];
            float4 av1 = *(const float4*)&As[kk][ty * 8 + 4];
            float4 bv0 = *(const float4*)&Bs[kk][tx * 8];
            float4 bv1 = *(const float4*)&Bs[kk][tx * 8 + 4];
            float aa[8] = {av0.x, av0.y, av0.z, av0.w, av1.x, av1.y, av1.z, av1.w};
            float bb[8] = {bv0.x, bv0.y, bv0.z, bv0.w, bv1.x, bv1.y, bv1.z, bv1.w};
#pragma unroll
            for (int i = 0; i < 8; i++)
#pragma unroll
                for (int j = 0; j < 8; j++) acc[i][j] += aa[i] * bb[j];
        }
        __syncthreads();
    }
    float bcache[8];
#pragma unroll
    for (int j = 0; j < 8; j++) bcache[j] = bias ? bias[c0 + tx * 8 + j] : 0.f;
#pragma unroll
    for (int i = 0; i < 8; i++) {
        int row = r0 + ty * 8 + i;
        float4 o0, o1;
        float v0 = acc[i][0] + bcache[0], v1 = acc[i][1] + bcache[1];
        float v2 = acc[i][2] + bcache[2], v3 = acc[i][3] + bcache[3];
        float v4 = acc[i][4] + bcache[4], v5 = acc[i][5] + bcache[5];
        float v6 = acc[i][6] + bcache[6], v7 = acc[i][7] + bcache[7];
        if (relu) {
            v0 = fmaxf(v0, 0.f); v1 = fmaxf(v1, 0.f); v2 = fmaxf(v2, 0.f); v3 = fmaxf(v3, 0.f);
            v4 = fmaxf(v4, 0.f); v5 = fmaxf(v5, 0.f); v6 = fmaxf(v6, 0.f); v7 = fmaxf(v7, 0.f);
        }
        o0.x = v0; o0.y = v1; o0.z = v2; o0.w = v3;
        o1.x = v4; o1.y = v5; o1.z = v6; o1.w = v7;
        *(float4*)&C[(long)row * N + c0 + tx * 8] = o0;
        *(float4*)&C[(long)row * N + c0 + tx * 8 + 4] = o1;
    }
}

// ---------------- dual-problem split-K 64x64 GEMM, atomic epilogue ----------------
// Requires M,N multiples of 64; Kc multiple of 16 dividing into K cleanly per chunk logic.
__global__ __launch_bounds__(256) void k_gemm_sk(
    const float* A0, const float* B0, float* C0, int M0, int N0, int K0, int lda0, int KS0, int Kc0,
    const float* A1, const float* B1, float* C1, int M1, int N1, int K1, int lda1, int KS1, int Kc1) {
    int z = blockIdx.z;
    const float* A; const float* Bm; float* C; int M, N, K, lda, kz, Kc;
    if (z < KS0) { A = A0; Bm = B0; C = C0; M = M0; N = N0; K = K0; lda = lda0; kz = z; Kc = Kc0; }
    else { A = A1; Bm = B1; C = C1; M = M1; N = N1; K = K1; lda = lda1; kz = z - KS0; Kc = Kc1; }
    int r0 = blockIdx.x * 64, c0 = blockIdx.y * 64;
    if (r0 >= M || c0 >= N) return;
    int kb = kz * Kc, ke = min(K, kb + Kc);
    __shared__ float As[16][68];
    __shared__ float Bs[16][64];
    int t = threadIdx.x;
    int tx = t & 15, ty = t >> 4;
    float acc[4][4] = {};
    int ar = t >> 2, aq = (t & 3) * 4;
    long abase = (long)(r0 + ar) * lda;
    int brow = t >> 4, bc = (t & 15) * 4;
    for (int k0 = kb; k0 < ke; k0 += 16) {
        float4 av = *(const float4*)(A + abase + k0 + aq);
        As[aq + 0][ar] = av.x; As[aq + 1][ar] = av.y; As[aq + 2][ar] = av.z; As[aq + 3][ar] = av.w;
        float4 bv = *(const float4*)(Bm + (long)(k0 + brow) * N + c0 + bc);
        *(float4*)&Bs[brow][bc] = bv;
        __syncthreads();
#pragma unroll
        for (int kk = 0; kk < 16; kk++) {
            float4 a4 = *(const float4*)&As[kk][ty * 4];
            float4 b4 = *(const float4*)&Bs[kk][tx * 4];
            float aa[4] = {a4.x, a4.y, a4.z, a4.w};
            float bb2[4] = {b4.x, b4.y, b4.z, b4.w};
#pragma unroll
            for (int i = 0; i < 4; i++)
#pragma unroll
                for (int j = 0; j < 4; j++) acc[i][j] += aa[i] * bb2[j];
        }
        __syncthreads();
    }
#pragma unroll
    for (int i = 0; i < 4; i++)
#pragma unroll
        for (int j = 0; j < 4; j++)
            atomicAdd(&C[(long)(r0 + ty * 4 + i) * N + c0 + tx * 4 + j], acc[i][j]);
}

// ---------------- small helpers ----------------
__global__ void k_bias2(float* C0, const float* b0, long n0, float* C1, const float* b1, long n1, int cols) {
    long idx = (long)blockIdx.x * 256 + threadIdx.x;
    long t0 = n0 * cols;
    if (idx < t0) C0[idx] = b0[idx % cols];
    else {
        long j = idx - t0;
        if (j < n1 * cols) C1[j] = b1[j % cols];
    }
}

__global__ void k_scale2(float* t0, const float* d0, long n0, float* t1, const float* d1, long n1, int cols) {
    long idx = (long)blockIdx.x * 256 + threadIdx.x;
    long s0 = n0 * cols;
    if (idx < s0) t0[idx] *= d0[idx / cols];
    else {
        long j = idx - s0;
        if (j < n1 * cols) t1[j] *= d1[j / cols];
    }
}

__global__ void k_fixup2(const float* g0, const float* t0, const float* adj0, const float* d0, float* C0, long n0,
                         const float* g1, const float* t1, const float* adj1, const float* d1, float* C1, long n1,
                         const float* bias, int cols) {
    long idx = (long)blockIdx.x * 256 + threadIdx.x;
    long s0 = n0 * cols;
    const float* g; const float* tt; const float* adj; const float* dv; float* C; long n, li;
    if (idx < s0) { g = g0; tt = t0; adj = adj0; dv = d0; C = C0; n = n0; li = idx; }
    else {
        li = idx - s0;
        if (li >= n1 * cols) return;
        g = g1; tt = t1; adj = adj1; dv = d1; C = C1; n = n1;
    }
    long i = li / cols; int j = li % cols;
    float v = dv[i] * (g[li] + (1.0f - adj[i * n + i]) * tt[li]) + bias[j];
    C[li] = fmaxf(v, 0.f);
}

__global__ void k_dense_deg2(const float* __restrict__ adj0, float* __restrict__ d0, int n0,
                             const float* __restrict__ adj1, float* __restrict__ d1, int n1) {
    int lane = threadIdx.x & 63;
    int row = (blockIdx.x * blockDim.x + threadIdx.x) >> 6;
    const float* adj; float* dv; int n, r;
    if (row < n0) { adj = adj0; dv = d0; n = n0; r = row; }
    else {
        r = row - n0;
        if (r >= n1) return;
        adj = adj1; dv = d1; n = n1;
    }
    const float* rp = adj + (long)r * n;
    float s = 0.f;
    for (int j = lane; j < n; j += 64) s += rp[j];
    for (int off = 32; off > 0; off >>= 1) s += __shfl_down(s, off, 64);
    if (lane == 0) {
        float deg = s - rp[r] + 1.0f;
        dv[r] = (deg > 0.f) ? 1.0f / sqrtf(deg) : 0.f;
    }
}

// df(M x 64) @ W4(64 x 16) -> C(M x 16), dual problem, 16 rows/block
__global__ void k_w4mm(const float* A0, float* C0, int M0, const float* A1, float* C1, int M1,
                       const float* __restrict__ W) {
    __shared__ float Ws[64][16];
    int t = threadIdx.x;
    for (int idx = t; idx < 1024; idx += 256) ((float*)Ws)[idx] = W[idx];
    __syncthreads();
    int bx = blockIdx.x;
    int nb0 = M0 / 16;
    const float* A; float* C; int rbase;
    if (bx < nb0) { A = A0; C = C0; rbase = bx * 16; }
    else { A = A1; C = C1; rbase = (bx - nb0) * 16; }
    int r = rbase + (t >> 4), c = t & 15;
    const float* arp = A + (long)r * 64;
    float acc = 0.f;
#pragma unroll
    for (int k = 0; k < 64; k += 4) {
        float4 a = *(const float4*)(arp + k);
        acc += a.x * Ws[k][c] + a.y * Ws[k + 1][c] + a.z * Ws[k + 2][c] + a.w * Ws[k + 3][c];
    }
    C[r * 16 + c] = acc;
}

// adj(n x n) @ u(n x 16) -> C(n x 16), dual, split-K, 16 rows/block, atomic
__global__ void k_adj16(const float* adj0, const float* u0, float* C0, int n0, int KS0, int Kc0,
                        const float* adj1, const float* u1, float* C1, int n1, int KS1, int Kc1) {
    int z = blockIdx.z;
    const float* adj; const float* u; float* C; int n, kz, Kc;
    if (z < KS0) { adj = adj0; u = u0; C = C0; n = n0; kz = z; Kc = Kc0; }
    else { adj = adj1; u = u1; C = C1; n = n1; kz = z - KS0; Kc = Kc1; }
    int r0 = blockIdx.x * 16;
    if (r0 >= n) return;
    int t = threadIdx.x;
    int r = r0 + (t >> 4), c = t & 15;
    int kb = kz * Kc, ke = min(n, kb + Kc);
    const float* arp = adj + (long)r * n;
    float acc = 0.f;
    for (int k = kb; k < ke; k += 4) {
        float4 a = *(const float4*)(arp + k);
        acc += a.x * u[(k + 0) * 16 + c] + a.y * u[(k + 1) * 16 + c]
             + a.z * u[(k + 2) * 16 + c] + a.w * u[(k + 3) * 16 + c];
    }
    atomicAdd(&C[r * 16 + c], acc);
}

// ---------------- stable top-K selection ----------------
__global__ void k_select(const float* __restrict__ cs, int* __restrict__ sel) {
    __shared__ float kk[240];
    int t = threadIdx.x;
    int b0 = blockIdx.x * 4;
    if (t < 240) kk[t] = cs[((long)(b0 * 60 + t)) * 64 + 63];
    __syncthreads();
    if (t < 240) {
        int lb = t / 60, i = t % 60;
        float key = kk[lb * 60 + i];
        int r = 0;
        for (int j = 0; j < 60; j++) {
            float kj = kk[lb * 60 + j];
            r += (kj > key) || (kj == key && j < i);
        }
        if (r < KSEL) sel[(b0 + lb) * KSEL + r] = (b0 + lb) * 60 + i;
    }
}

// ---------------- conv1 (stride-64) + relu + maxpool2 ----------------
__global__ __launch_bounds__(256) void k_conv1_pool(const float* __restrict__ cs, const int* __restrict__ sel,
                                                    const float* __restrict__ c1w, const float* __restrict__ c1b,
                                                    float* __restrict__ po) {
    __shared__ float xs[30 * 64];
    __shared__ float w[64 * 129];
    __shared__ float cv[30 * 128];
    int t = threadIdx.x, b = blockIdx.x;
    for (int idx = t; idx < 1920; idx += 256) {
        int i = idx >> 6, c = idx & 63;
        xs[idx] = cs[(long)sel[b * KSEL + i] * 64 + c];
    }
    for (int f = t; f < 8192; f += 256) {
        int oc = f >> 6, tt = f & 63;
        w[tt * 129 + oc] = c1w[f];
    }
    __syncthreads();
    int oc = t & 127, half = t >> 7;
    float acc[15];
#pragma unroll
    for (int k = 0; k < 15; k++) acc[k] = 0.f;
    int kbase = half * 15;
    for (int tt = 0; tt < 64; tt++) {
        float wv = w[tt * 129 + oc];
#pragma unroll
        for (int k = 0; k < 15; k++) acc[k] += wv * xs[(kbase + k) * 64 + tt];
    }
    float bb = c1b[oc];
#pragma unroll
    for (int k = 0; k < 15; k++) cv[(kbase + k) * 128 + oc] = fmaxf(acc[k] + bb, 0.f);
    __syncthreads();
    for (int idx = t; idx < 1920; idx += 256) {
        int k2 = idx >> 7, c = idx & 127;
        po[(long)b * 1920 + idx] = fmaxf(cv[(2 * k2) * 128 + c], cv[(2 * k2 + 1) * 128 + c]);
    }
}

// ---------------- weight prep ----------------
__global__ void k_w2col(const float* __restrict__ c2w, float* __restrict__ o) {
    int idx = blockIdx.x * blockDim.x + threadIdx.x;
    if (idx >= 640 * 256) return;
    int r = idx >> 8, oc = idx & 255;
    int tap = r >> 7, ic = r & 127;
    o[idx] = c2w[(oc * 128 + ic) * 5 + tap];
}

__global__ void k_w1p(const float* __restrict__ w, float* __restrict__ o) {
    int idx = blockIdx.x * blockDim.x + threadIdx.x;
    if (idx >= 2816 * 128) return;
    int r = idx >> 7, j = idx & 127;
    int tt = r / 256, oc = r % 256;
    o[idx] = w[(oc * 11 + tt) * 128 + j];
}

// ---------------- lin2 + bn (applies relu to lin1 output on load) ----------------
__global__ void k_lin2_bn(const float* __restrict__ x, const float* __restrict__ w,
                          const float* __restrict__ b, const float* __restrict__ g,
                          const float* __restrict__ bb, float* __restrict__ o) {
    int t = blockIdx.x * blockDim.x + threadIdx.x;
    int j = t & 31, bi = t >> 5;
    const float* xr = x + (long)bi * 128;
    float acc = b[j];
    for (int k = 0; k < 128; k++) acc += fmaxf(xr[k], 0.f) * w[k * 32 + j];
    o[bi * 32 + j] = fmaxf(acc * g[j] + bb[j], 0.f);
}

// ---------------- final fused MLP ----------------
__global__ __launch_bounds__(256) void k_final(const float* __restrict__ hfin, const int* __restrict__ node,
                                               const float* __restrict__ dio, const float* __restrict__ dro,
                                               const float* __restrict__ pp,
                                               const float* __restrict__ fw, const float* __restrict__ fb,
                                               const float* __restrict__ f2w, const float* __restrict__ f2b,
                                               float* __restrict__ out) {
    __shared__ float w[64 * 32];
    __shared__ float w2[32];
    int t = threadIdx.x;
    for (int f = t; f < 2048; f += 256) w[f] = fw[f];
    if (t < 32) w2[t] = f2w[t];
    __syncthreads();
    int b = blockIdx.x * 256 + t;
    float p = *pp, q = 1.0f - p;
    float zin[64];
#pragma unroll
    for (int i = 0; i < 32; i++) zin[i] = hfin[b * 32 + i] * p;
    int n0 = node[b * 2], n1 = node[b * 2 + 1];
#pragma unroll
    for (int i = 0; i < 16; i++) zin[32 + i] = dio[n0 * 16 + i] * q;
#pragma unroll
    for (int i = 0; i < 16; i++) zin[48 + i] = dro[n1 * 16 + i] * q;
    float res = f2b[0];
    for (int j = 0; j < 32; j++) {
        float acc = fb[j];
#pragma unroll
        for (int i = 0; i < 64; i++) acc += zin[i] * w[i * 32 + j];
        res += fmaxf(acc, 0.f) * w2[j];
    }
    out[b] = res;
}

// ---------------- host ----------------
extern "C" void kernel_launch(void* const* d_in, const int* in_sizes, int n_in,
                              void* d_out, int out_size, void* d_ws, size_t ws_size,
                              hipStream_t stream) {
    const float* x        = (const float*)d_in[0];
    const int*   ei       = (const int*)d_in[1];
    const int*   node     = (const int*)d_in[3];
    const float* di_sim   = (const float*)d_in[4];
    const float* dr_sim   = (const float*)d_in[5];
    const float* drug_adj = (const float*)d_in[6];
    const float* dis_adj  = (const float*)d_in[7];
    const float* p        = (const float*)d_in[8];
    const float* W1 = (const float*)d_in[9],  *b1 = (const float*)d_in[10];
    const float* W2 = (const float*)d_in[11], *b2 = (const float*)d_in[12];
    const float* W3 = (const float*)d_in[13], *b3 = (const float*)d_in[14];
    const float* W4 = (const float*)d_in[15], *b4 = (const float*)d_in[16];
    const float* lin_di_w = (const float*)d_in[17], *lin_di_b = (const float*)d_in[18];
    const float* lin_dr_w = (const float*)d_in[19], *lin_dr_b = (const float*)d_in[20];
    const float* c1w = (const float*)d_in[21], *c1b = (const float*)d_in[22];
    const float* c2w = (const float*)d_in[23], *c2b = (const float*)d_in[24];
    const float* lin1w = (const float*)d_in[25], *lin1b = (const float*)d_in[26];
    const float* lin2w = (const float*)d_in[27], *lin2b = (const float*)d_in[28];
    const float* bng = (const float*)d_in[29], *bnb = (const float*)d_in[30];
    const float* fcsw = (const float*)d_in[31], *fcsb = (const float*)d_in[32];
    const float* fcs2w = (const float*)d_in[33], *fcs2b = (const float*)d_in[34];

    char* ws = (char*)d_ws;
    size_t o = 0;
    auto alloc = [&](size_t bytes) { size_t r = o; o += (bytes + 255) & ~(size_t)255; return r; };
    int*   csr     = (int*)(ws + alloc((size_t)NE * 4));
    int*   degcnt  = (int*)(ws + alloc((size_t)NN * 4));
    int*   rowp    = (int*)(ws + alloc((size_t)NN * 4));
    int*   fillc   = (int*)(ws + alloc((size_t)NN * 4));
    float* dinvn   = (float*)(ws + alloc((size_t)NN * 4));
    float* hbuf    = (float*)(ws + alloc((size_t)NN * 32 * 4));  // reused as pool_out (B*15*128)
    float* cs      = (float*)(ws + alloc((size_t)NN * 64 * 4));  // reused as act2 (B*11*256)
    int*   sel     = (int*)(ws + alloc((size_t)NB * KSEL * 4));
    float* lin1o   = (float*)(ws + alloc((size_t)NB * 128 * 4));
    float* hfin    = (float*)(ws + alloc((size_t)NB * 32 * 4));
    float* w2col   = (float*)(ws + alloc((size_t)640 * 256 * 4));
    float* w1p     = (float*)(ws + alloc((size_t)2816 * 128 * 4));
    int*   sums    = (int*)(ws + alloc(256 * 4));
    float* ddin_di = (float*)(ws + alloc((size_t)NDRUG * 4));
    float* ddin_dr = (float*)(ws + alloc((size_t)NDIS * 4));
    float* de_di   = (float*)(ws + alloc((size_t)NDRUG * 256 * 4));
    float* de_dr   = (float*)(ws + alloc((size_t)NDIS * 256 * 4));
    float* df_di   = (float*)(ws + alloc((size_t)NDRUG * 64 * 4));
    float* df_dr   = (float*)(ws + alloc((size_t)NDIS * 64 * 4));
    float* do_di   = (float*)(ws + alloc((size_t)NDRUG * 16 * 4));
    float* do_dr   = (float*)(ws + alloc((size_t)NDIS * 16 * 4));
    // zero-init (atomic accumulation targets) -- contiguous block, one memset
    size_t zbase = o;
    float* dt_di   = (float*)(ws + alloc((size_t)NDRUG * 64 * 4));
    float* dt_dr   = (float*)(ws + alloc((size_t)NDIS * 64 * 4));
    float* dg_di   = (float*)(ws + alloc((size_t)NDRUG * 64 * 4));
    float* dg_dr   = (float*)(ws + alloc((size_t)NDIS * 64 * 4));
    float* dt2_di  = (float*)(ws + alloc((size_t)NDRUG * 16 * 4));
    float* dt2_dr  = (float*)(ws + alloc((size_t)NDIS * 16 * 4));
    float* dg2_di  = (float*)(ws + alloc((size_t)NDRUG * 16 * 4));
    float* dg2_dr  = (float*)(ws + alloc((size_t)NDIS * 16 * 4));
    size_t zsize = o - zbase;
    float* pool = hbuf;   // alias after GCN done
    float* act2 = cs;     // alias after conv1 done

    hipMemsetAsync(degcnt, 0, (size_t)NN * 4, stream);
    hipMemsetAsync(fillc, 0, (size_t)NN * 4, stream);
    hipMemsetAsync(ws + zbase, 0, zsize, stream);

    // CSR build
    k_count<<<2048, 256, 0, stream>>>(ei, degcnt);
    k_dinv<<<(NN + 255) / 256, 256, 0, stream>>>(degcnt, dinvn);
    k_block_sums<<<240, 256, 0, stream>>>(degcnt, sums);
    k_scan_sums<<<1, 256, 0, stream>>>(sums, 240);
    k_scan_blocks<<<240, 256, 0, stream>>>(degcnt, sums, rowp);
    k_fill<<<2048, 256, 0, stream>>>(ei, rowp, fillc, csr);

    // GCN conv 1: h = x@W1 ; x1 = relu(agg + b1) -> cs[:, 0:32]
    k_xw<<<NN / 64, 256, 0, stream>>>(x, W1, hbuf, 64, 64);
    k_gcn_agg<<<NN / 32, 256, 0, stream>>>(hbuf, csr, rowp, degcnt, dinvn, b1, cs, 0);
    // GCN conv 2: h = x1@W2 ; x2 -> cs[:, 32:64]
    k_xw<<<NN / 64, 256, 0, stream>>>(cs, W2, hbuf, 32, 64);
    k_gcn_agg<<<NN / 32, 256, 0, stream>>>(hbuf, csr, rowp, degcnt, dinvn, b2, cs, 32);

    // stable top-K selection per batch
    k_select<<<NB / 4, 256, 0, stream>>>(cs, sel);

    // weight prep
    k_w2col<<<(640 * 256 + 255) / 256, 256, 0, stream>>>(c2w, w2col);
    k_w1p<<<(2816 * 128 + 255) / 256, 256, 0, stream>>>(lin1w, w1p);

    // conv1 + pool  (writes pool = hbuf, reads cs)
    k_conv1_pool<<<NB, 256, 0, stream>>>(cs, sel, c1w, c1b, pool);

    // conv2 as im2col GEMM: (B*11, 640) @ (640,256) -> act2 (= cs)
    k_gemm128<1><<<dim3(45056 / 128, 2), 256, 0, stream>>>(pool, w2col, act2, c2b, 256, 640, 0, 1);

    // lin1 via split-K (relu folded into lin2 read): init bias, accumulate
    k_bias2<<<(NB * 128 + 255) / 256, 256, 0, stream>>>(lin1o, lin1b, NB, lin1o, lin1b, 0, 128);
    k_gemm_sk<<<dim3(NB / 64, 2, 11), 256, 0, stream>>>(
        act2, w1p, lin1o, NB, 128, 2816, 2816, 11, 256,
        act2, w1p, lin1o, 0, 128, 2816, 2816, 0, 256);
    k_lin2_bn<<<NB * 32 / 256, 256, 0, stream>>>(lin1o, lin2w, lin2b, bng, bnb, hfin);

    // ---- dense drug (p0) + disease (p1) paths, fused stage-wise ----
    k_dense_deg2<<<(NDRUG + NDIS) * 64 / 256, 256, 0, stream>>>(drug_adj, ddin_di, NDRUG, dis_adj, ddin_dr, NDIS);
    // de = sim @ lin_w + bias
    k_bias2<<<((NDRUG + NDIS) * 256 + 255) / 256, 256, 0, stream>>>(de_di, lin_di_b, NDRUG, de_dr, lin_dr_b, NDIS, 256);
    k_gemm_sk<<<dim3(NDIS / 64, 4, 12), 256, 0, stream>>>(
        di_sim, lin_di_w, de_di, NDRUG, 256, NDRUG, NDRUG, 4, 256,
        dr_sim, lin_dr_w, de_dr, NDIS, 256, NDIS, NDIS, 8, 256);
    // dt = de @ W3 (zero-inited)
    k_gemm_sk<<<dim3(NDIS / 64, 1, 8), 256, 0, stream>>>(
        de_di, W3, dt_di, NDRUG, 64, 256, 256, 4, 64,
        de_dr, W3, dt_dr, NDIS, 64, 256, 256, 4, 64);
    // u = dinv * dt
    k_scale2<<<((NDRUG + NDIS) * 64 + 255) / 256, 256, 0, stream>>>(dt_di, ddin_di, NDRUG, dt_dr, ddin_dr, NDIS, 64);
    // g = adj @ u (zero-inited)
    k_gemm_sk<<<dim3(NDIS / 64, 1, 24), 256, 0, stream>>>(
        drug_adj, dt_di, dg_di, NDRUG, 64, NDRUG, NDRUG, 8, 128,
        dis_adj, dt_dr, dg_dr, NDIS, 64, NDIS, NDIS, 16, 128);
    // df = relu(dinv*(g + (1-diag)*u) + b3)
    k_fixup2<<<((NDRUG + NDIS) * 64 + 255) / 256, 256, 0, stream>>>(
        dg_di, dt_di, drug_adj, ddin_di, df_di, NDRUG,
        dg_dr, dt_dr, dis_adj, ddin_dr, df_dr, NDIS, b3, 64);
    // dt2 = df @ W4
    k_w4mm<<<(NDRUG + NDIS) / 16, 256, 0, stream>>>(df_di, dt2_di, NDRUG, df_dr, dt2_dr, NDIS, W4);
    k_scale2<<<((NDRUG + NDIS) * 16 + 255) / 256, 256, 0, stream>>>(dt2_di, ddin_di, NDRUG, dt2_dr, ddin_dr, NDIS, 16);
    // g2 = adj @ u2 (zero-inited)
    k_adj16<<<dim3(NDIS / 16, 1, 6), 256, 0, stream>>>(
        drug_adj, dt2_di, dg2_di, NDRUG, 2, 512,
        dis_adj, dt2_dr, dg2_dr, NDIS, 4, 512);
    k_fixup2<<<((NDRUG + NDIS) * 16 + 255) / 256, 256, 0, stream>>>(
        dg2_di, dt2_di, drug_adj, ddin_di, do_di, NDRUG,
        dg2_dr, dt2_dr, dis_adj, ddin_dr, do_dr, NDIS, b4, 16);

    // final
    k_final<<<NB / 256, 256, 0, stream>>>(hfin, node, do_di, do_dr, p, fcsw, fcsb, fcs2w, fcs2b, (float*)d_out);
}